// Round 2
// baseline (2146.922 us; speedup 1.0000x reference)
//
#include <hip/hip_runtime.h>

// GPT-style forward pass on MI355X. B=16,T=256,D=512,H=8,L=8,HS=64,V=32000.
// bf16 MFMA GEMMs (builtin v_mfma_f32_16x16x32_bf16), f32 residual/LN/softmax/loss.
// Workspace ~184 MB (weights repacked to [N][K] bf16 each launch).

typedef unsigned short ushort_t;
typedef float f32x4 __attribute__((ext_vector_type(4)));
typedef short bf16x8 __attribute__((ext_vector_type(8)));

#define DEVI __device__ __forceinline__

DEVI ushort_t f2bf(float f) {
  union { float f; unsigned u; } x; x.f = f;
  return (ushort_t)((x.u + 0x7fffu + ((x.u >> 16) & 1u)) >> 16);
}

DEVI void load_lds16(const void* g, void* l) {
  __builtin_amdgcn_global_load_lds(
      (const __attribute__((address_space(1))) void*)(g),
      (__attribute__((address_space(3))) void*)(l),
      16, 0, 0);
}

// ---------------------------------------------------------------------------
// Generic bf16 GEMM: C[M,N] = A[M,K] * B^T[N,K]  (both row-major, leading dims
// lda/ldb). LDS staging via global_load_lds, XOR swizzle (slot ^= row&7)
// applied on the *global source* (linear LDS dest, rule #21) so fragment
// ds_read_b128 is bank-conflict-free. Batch offsets: off(z)=(z/zdiv)*S1+(z%zdiv)*S2.
// ---------------------------------------------------------------------------
template<int BM,int BN,int BK,int WGM,int WGN,bool BIAS,bool RES,bool RELU,bool OUTBF>
__global__ __launch_bounds__(WGM*WGN*64)
void gemm_k(const ushort_t* __restrict__ A, int lda, long aS1, long aS2,
            const ushort_t* __restrict__ B, int ldb, long bS1, long bS2,
            void* __restrict__ Cv, int ldc, long cS1, long cS2,
            const float* __restrict__ bias,
            const float* __restrict__ res,
            int K, int zdiv)
{
  constexpr int WAVES = WGM*WGN;
  constexpr int WM = BM/WGM, WN = BN/WGN;
  constexpr int FM = WM/16, FN = WN/16;
  constexpr int CHA = BM*BK*2/1024;   // 1KB staging chunks
  constexpr int CHB = BN*BK*2/1024;
  constexpr int SMASK = BK/8 - 1;     // 16B-granule slots per row - 1
  static_assert(CHA % WAVES == 0 && CHB % WAVES == 0, "staging chunks");
  static_assert(BK == 64, "swizzle assumes 128B rows");

  __shared__ __align__(16) ushort_t As[BM*BK];
  __shared__ __align__(16) ushort_t Bs[BN*BK];

  const int tid  = threadIdx.x;
  const int lane = tid & 63;
  const int wave = tid >> 6;
  const int z  = blockIdx.z;
  const int zq = z / zdiv, zr = z - zq*zdiv;

  const int bm = blockIdx.y*BM, bn = blockIdx.x*BN;
  A += (long)zq*aS1 + (long)zr*aS2 + (long)bm*lda;
  B += (long)zq*bS1 + (long)zr*bS2 + (long)bn*ldb;
  const long coff = (long)zq*cS1 + (long)zr*cS2;

  const int wm = (wave/WGN)*WM, wn = (wave%WGN)*WN;

  f32x4 acc[FM][FN] = {};

  for (int k0 = 0; k0 < K; k0 += BK) {
    // ---- stage A,B tiles (linear LDS dest, inverse-swizzled global source)
    #pragma unroll
    for (int c = 0; c < CHA/WAVES; ++c) {
      const int ch  = wave + c*WAVES;
      const int ob  = ch*1024 + lane*16;
      const int row = ob >> 7;               // 128B per row (BK=64 bf16)
      const int g   = ((ob >> 4) & SMASK) ^ (row & SMASK);
      load_lds16(A + row*lda + (k0 + g*8), (char*)As + ch*1024);
    }
    #pragma unroll
    for (int c = 0; c < CHB/WAVES; ++c) {
      const int ch  = wave + c*WAVES;
      const int ob  = ch*1024 + lane*16;
      const int row = ob >> 7;
      const int g   = ((ob >> 4) & SMASK) ^ (row & SMASK);
      load_lds16(B + row*ldb + (k0 + g*8), (char*)Bs + ch*1024);
    }
    __syncthreads();   // drains vmcnt before s_barrier

    // ---- fragments for both k-substeps, then MFMA cluster
    bf16x8 af[2][FM], bfr[2][FN];
    #pragma unroll
    for (int s = 0; s < 2; ++s) {
      const int g = (lane >> 4) + s*4;
      #pragma unroll
      for (int i = 0; i < FM; ++i) {
        const int row = wm + i*16 + (lane & 15);
        af[s][i] = *(const bf16x8*)((const char*)As + row*(BK*2) + ((g ^ (row & SMASK))*16));
      }
      #pragma unroll
      for (int j = 0; j < FN; ++j) {
        const int row = wn + j*16 + (lane & 15);
        bfr[s][j] = *(const bf16x8*)((const char*)Bs + row*(BK*2) + ((g ^ (row & SMASK))*16));
      }
    }
    #pragma unroll
    for (int s = 0; s < 2; ++s)
      #pragma unroll
      for (int i = 0; i < FM; ++i)
        #pragma unroll
        for (int j = 0; j < FN; ++j)
          acc[i][j] = __builtin_amdgcn_mfma_f32_16x16x32_bf16(af[s][i], bfr[s][j], acc[i][j], 0, 0, 0);
    __syncthreads();
  }

  // ---- epilogue: C/D layout (verified m89/m91): col = lane&15, row = (lane>>4)*4+r
  float*    Cf = (float*)Cv;
  ushort_t* Cb = (ushort_t*)Cv;
  #pragma unroll
  for (int i = 0; i < FM; ++i) {
    #pragma unroll
    for (int j = 0; j < FN; ++j) {
      const int col = bn + wn + j*16 + (lane & 15);
      #pragma unroll
      for (int r = 0; r < 4; ++r) {
        const int row = bm + wm + i*16 + (lane >> 4)*4 + r;
        float v = acc[i][j][r];
        if (BIAS) v += bias[col];
        if (RES)  v += res[coff + (long)row*ldc + col];
        if (RELU) v = fmaxf(v, 0.0f);
        const long o = coff + (long)row*ldc + col;
        if (OUTBF) Cb[o] = f2bf(v); else Cf[o] = v;
      }
    }
  }
}

// ---------------------------------------------------------------------------
// transpose + f32->bf16 cast: out[c][r] = in[r][c]; 32x32 LDS tiles.
// ---------------------------------------------------------------------------
__global__ void transpose_cast(const float* __restrict__ in, ushort_t* __restrict__ out,
                               int ldin, int ldout, int zdiv,
                               long inS1, long inS2, long outS1, long outS2)
{
  const int z = blockIdx.z;
  in  += (long)(z/zdiv)*inS1  + (long)(z%zdiv)*inS2;
  out += (long)(z/zdiv)*outS1 + (long)(z%zdiv)*outS2;
  __shared__ float t[32][33];
  const int c0 = blockIdx.x*32, r0 = blockIdx.y*32;
  const int tc = threadIdx.x & 31, tr8 = threadIdx.x >> 5;
  #pragma unroll
  for (int p = 0; p < 4; ++p) {
    const int r = tr8 + p*8;
    t[r][tc] = in[(long)(r0+r)*ldin + c0+tc];
  }
  __syncthreads();
  #pragma unroll
  for (int p = 0; p < 4; ++p) {
    const int c = tr8 + p*8;
    out[(long)(c0+c)*ldout + r0+tc] = f2bf(t[tc][c]);
  }
}

// x[b*T+t][:] = tok_emb[idx[b*T+t]][:] + pos_emb[t][:]
__global__ void embed_kernel(const int* __restrict__ idx, const float* __restrict__ tok,
                             const float* __restrict__ pos, float* __restrict__ x)
{
  const int row = blockIdx.x;
  const int t = row & 255;
  const int id = idx[row];
  const float4 a = ((const float4*)(tok + (long)id*512))[threadIdx.x];
  const float4 p = ((const float4*)(pos + (long)t*512))[threadIdx.x];
  float4 o; o.x = a.x+p.x; o.y = a.y+p.y; o.z = a.z+p.z; o.w = a.w+p.w;
  ((float4*)(x + (long)row*512))[threadIdx.x] = o;
}

// LayerNorm over D=512, f32 in -> bf16 out. 128 threads/row.
__global__ void ln_kernel(const float* __restrict__ x, const float* __restrict__ s,
                          const float* __restrict__ b, ushort_t* __restrict__ out)
{
  const int row = blockIdx.x;
  const float4 v = ((const float4*)(x + (long)row*512))[threadIdx.x];
  float sum = v.x+v.y+v.z+v.w;
  float sq  = v.x*v.x+v.y*v.y+v.z*v.z+v.w*v.w;
  #pragma unroll
  for (int o = 32; o; o >>= 1) { sum += __shfl_xor(sum, o); sq += __shfl_xor(sq, o); }
  __shared__ float red[4];
  if ((threadIdx.x & 63) == 0) { red[(threadIdx.x>>6)*2] = sum; red[(threadIdx.x>>6)*2+1] = sq; }
  __syncthreads();
  sum = red[0] + red[2]; sq = red[1] + red[3];
  const float m = sum * (1.f/512.f);
  const float var = sq * (1.f/512.f) - m*m;
  const float rstd = rsqrtf(var + 1e-5f);
  const float4 sv = ((const float4*)s)[threadIdx.x];
  const float4 bv = ((const float4*)b)[threadIdx.x];
  ushort4 o4;
  o4.x = f2bf((v.x-m)*rstd*sv.x + bv.x);
  o4.y = f2bf((v.y-m)*rstd*sv.y + bv.y);
  o4.z = f2bf((v.z-m)*rstd*sv.z + bv.z);
  o4.w = f2bf((v.w-m)*rstd*sv.w + bv.w);
  ((ushort4*)(out + (long)row*512))[threadIdx.x] = o4;
}

// causal softmax over 256-wide rows; scale applied here; f32 in -> bf16 out.
// 4 rows/block (one wave per row).
__global__ void softmax_kernel(const float* __restrict__ sc, ushort_t* __restrict__ wei)
{
  const int r = blockIdx.x*4 + (threadIdx.x >> 6);
  const int lane = threadIdx.x & 63;
  const int i = r & 255;
  const float4 v = ((const float4*)(sc + (long)r*256))[lane];
  const float scale = 0.04419417382415922f;  // 512^-0.5 (source scales by D)
  const int j0 = lane*4;
  float vals[4] = {v.x, v.y, v.z, v.w};
  float mx = -3.4e38f;
  #pragma unroll
  for (int q = 0; q < 4; ++q) {
    vals[q] = (j0 + q <= i) ? vals[q]*scale : -3.4e38f;
    mx = fmaxf(mx, vals[q]);
  }
  #pragma unroll
  for (int o = 32; o; o >>= 1) mx = fmaxf(mx, __shfl_xor(mx, o));
  float e[4]; float ssum = 0.f;
  #pragma unroll
  for (int q = 0; q < 4; ++q) { e[q] = (j0+q <= i) ? __expf(vals[q]-mx) : 0.f; ssum += e[q]; }
  #pragma unroll
  for (int o = 32; o; o >>= 1) ssum += __shfl_xor(ssum, o);
  const float inv = 1.f / ssum;
  ushort4 o4;
  o4.x = f2bf(e[0]*inv); o4.y = f2bf(e[1]*inv); o4.z = f2bf(e[2]*inv); o4.w = f2bf(e[3]*inv);
  ((ushort4*)(wei + (long)r*256))[lane] = o4;
}

// vT[(b,h)][d][t] = kqv[(b*256+t)*1536 + 1024 + h*64 + d]  (per-(b,h) transpose)
__global__ void vt_kernel(const ushort_t* __restrict__ kqv, ushort_t* __restrict__ vT)
{
  const int z = blockIdx.x;            // b*8+h
  const int b = z >> 3, h = z & 7;
  __shared__ ushort_t t[256*65];
  const ushort_t* src = kqv + (long)b*393216 + 1024 + h*64;
  for (int it = 0; it < 64; ++it) {
    const int tt = it*4 + (threadIdx.x >> 6);
    const int d  = threadIdx.x & 63;
    t[tt*65 + d] = src[(long)tt*1536 + d];
  }
  __syncthreads();
  ushort_t* dst = vT + (long)z*16384;
  for (int d4 = 0; d4 < 64; ++d4)
    dst[(long)d4*256 + threadIdx.x] = t[threadIdx.x*65 + d4];
}

__global__ void zero_kernel(float* p) { if (threadIdx.x == 0) p[0] = 0.f; }

// per-row online logsumexp over V=32000; accumulate (lse - logit[target]).
__global__ void loss_kernel(const float* __restrict__ logits, const int* __restrict__ tgt,
                            float* __restrict__ acc)
{
  const int row = blockIdx.x;
  const float* lr = logits + (long)row*32000;
  float m = -3.4e38f, s = 0.f;
  for (int j = threadIdx.x; j < 32000; j += 256) {
    const float v = lr[j];
    if (v > m) { s *= __expf(m - v); m = v; }
    s += __expf(v - m);
  }
  #pragma unroll
  for (int o = 32; o; o >>= 1) {
    const float om = __shfl_xor(m, o), os = __shfl_xor(s, o);
    const float M = fmaxf(m, om);
    s = s*__expf(m - M) + os*__expf(om - M);
    m = M;
  }
  __shared__ float sm[4], ss[4];
  if ((threadIdx.x & 63) == 0) { sm[threadIdx.x>>6] = m; ss[threadIdx.x>>6] = s; }
  __syncthreads();
  if (threadIdx.x == 0) {
    const float M = fmaxf(fmaxf(sm[0],sm[1]), fmaxf(sm[2],sm[3]));
    const float S = ss[0]*__expf(sm[0]-M) + ss[1]*__expf(sm[1]-M)
                  + ss[2]*__expf(sm[2]-M) + ss[3]*__expf(sm[3]-M);
    atomicAdd(acc, (M + logf(S)) - lr[tgt[row]]);
  }
}

__global__ void final_kernel(const float* __restrict__ acc, float* __restrict__ out)
{
  if (threadIdx.x == 0) out[0] = acc[0] * (1.0f/4096.0f);
}

// ---------------------------------------------------------------------------
extern "C" void kernel_launch(void* const* d_in, const int* in_sizes, int n_in,
                              void* d_out, int out_size, void* d_ws, size_t ws_size,
                              hipStream_t stream)
{
  (void)in_sizes; (void)n_in; (void)out_size; (void)ws_size;
  const int*   idx     = (const int*)  d_in[0];
  const int*   targets = (const int*)  d_in[1];
  const float* tok_emb = (const float*)d_in[2];
  const float* pos_emb = (const float*)d_in[3];
  const float* ln1_s   = (const float*)d_in[4];
  const float* ln1_b   = (const float*)d_in[5];
  const float* wkW     = (const float*)d_in[6];
  const float* wqW     = (const float*)d_in[7];
  const float* wvW     = (const float*)d_in[8];
  const float* w_proj  = (const float*)d_in[9];
  const float* b_proj  = (const float*)d_in[10];
  const float* ln2_s   = (const float*)d_in[11];
  const float* ln2_b   = (const float*)d_in[12];
  const float* w1      = (const float*)d_in[13];
  const float* b1      = (const float*)d_in[14];
  const float* w2      = (const float*)d_in[15];
  const float* b2      = (const float*)d_in[16];
  const float* lnf_s   = (const float*)d_in[17];
  const float* lnf_b   = (const float*)d_in[18];
  const float* w_lm    = (const float*)d_in[19];
  const float* b_lm    = (const float*)d_in[20];

  char* ws = (char*)d_ws;   // ~184 MB used
  float*    x      = (float*)   (ws + 0);          // [4096][512] f32
  ushort_t* kqv    = (ushort_t*)(ws + 8388608);    // [4096][1536] bf16 (k|q|v)
  ushort_t* h      = (ushort_t*)(ws + 20971520);   // [4096][512] bf16
  ushort_t* vT     = (ushort_t*)(ws + 25165824);   // [128][64][256] bf16
  ushort_t* attno  = (ushort_t*)(ws + 29360128);   // [4096][512] bf16
  ushort_t* ffn    = (ushort_t*)(ws + 33554432);   // [4096][2048] bf16
  float*    scores = (float*)   (ws + 50331648);   // [128][256][256] f32
  ushort_t* wei    = (ushort_t*)(ws + 83886080);   // [128][256][256] bf16
  ushort_t* wkqvT  = (ushort_t*)(ws + 100663296);  // [8][1536][512] bf16
  ushort_t* wprojT = (ushort_t*)(ws + 113246208);  // [8][512][512] bf16
  ushort_t* w1T    = (ushort_t*)(ws + 117440512);  // [8][2048][512] bf16
  ushort_t* w2T    = (ushort_t*)(ws + 134217728);  // [8][512][2048] bf16
  ushort_t* wlmT   = (ushort_t*)(ws + 150994944);  // [32000][512] bf16
  float*    lacc   = (float*)   (ws + 183762944);

  float* logits = (float*)d_out;
  const dim3 b256(256);

  // --- weight repacks (every launch; inputs restored pristine each call)
  transpose_cast<<<dim3(2,16,64),  b256, 0, stream>>>(wkW, wkqvT,          64, 512, 8, 262144, 32768, 786432, 32768);
  transpose_cast<<<dim3(2,16,64),  b256, 0, stream>>>(wqW, wkqvT + 262144, 64, 512, 8, 262144, 32768, 786432, 32768);
  transpose_cast<<<dim3(2,16,64),  b256, 0, stream>>>(wvW, wkqvT + 524288, 64, 512, 8, 262144, 32768, 786432, 32768);
  transpose_cast<<<dim3(16,16,8),  b256, 0, stream>>>(w_proj, wprojT, 512, 512, 1, 262144, 0, 262144, 0);
  transpose_cast<<<dim3(64,16,8),  b256, 0, stream>>>(w1, w1T, 2048, 512, 1, 1048576, 0, 1048576, 0);
  transpose_cast<<<dim3(16,64,8),  b256, 0, stream>>>(w2, w2T, 512, 2048, 1, 1048576, 0, 1048576, 0);
  transpose_cast<<<dim3(1000,16,1),b256, 0, stream>>>(w_lm, wlmT, 32000, 512, 1, 0,0,0,0);

  embed_kernel<<<4096, 128, 0, stream>>>(idx, tok_emb, pos_emb, x);

  for (int l = 0; l < 8; ++l) {
    ln_kernel<<<4096, 128, 0, stream>>>(x, ln1_s + l*512, ln1_b + l*512, h);
    // kqv = h @ [Wk|Wq|Wv]   (M=4096,N=1536,K=512)
    gemm_k<128,128,64,2,2,false,false,false,true><<<dim3(12,32,1), b256, 0, stream>>>(
        h, 512, 0,0,  wkqvT + (long)l*786432, 512, 0,0,
        kqv, 1536, 0,0, nullptr, nullptr, 512, 1);
    vt_kernel<<<128, b256, 0, stream>>>(kqv, vT);
    // scores[z] = K_z @ Q_z^T  (M=256,N=256,K=64; z=b*8+h)
    gemm_k<128,128,64,2,2,false,false,false,false><<<dim3(2,2,128), b256, 0, stream>>>(
        kqv, 1536, 393216, 64,  kqv + 512, 1536, 393216, 64,
        scores, 256, 524288, 65536, nullptr, nullptr, 64, 8);
    softmax_kernel<<<8192, b256, 0, stream>>>(scores, wei);
    // attno = wei @ V  (M=256,N=64,K=256 per z), written as [4096][512] at col h*64
    gemm_k<64,64,64,2,2,false,false,false,true><<<dim3(1,4,128), b256, 0, stream>>>(
        wei, 256, 524288, 65536,  vT, 256, 131072, 16384,
        attno, 512, 131072, 64, nullptr, nullptr, 256, 8);
    // x += attno @ Wproj + b_proj
    gemm_k<128,128,64,2,2,true,true,false,false><<<dim3(4,32,1), b256, 0, stream>>>(
        attno, 512, 0,0,  wprojT + (long)l*262144, 512, 0,0,
        x, 512, 0,0, b_proj + l*512, x, 512, 1);
    ln_kernel<<<4096, 128, 0, stream>>>(x, ln2_s + l*512, ln2_b + l*512, h);
    // ffn = relu(h @ W1 + b1)
    gemm_k<128,128,64,2,2,true,false,true,true><<<dim3(16,32,1), b256, 0, stream>>>(
        h, 512, 0,0,  w1T + (long)l*1048576, 512, 0,0,
        ffn, 2048, 0,0, b1 + l*2048, nullptr, 512, 1);
    // x += ffn @ W2 + b2
    gemm_k<128,128,64,2,2,true,true,false,false><<<dim3(4,32,1), b256, 0, stream>>>(
        ffn, 2048, 0,0,  w2T + (long)l*1048576, 2048, 0,0,
        x, 512, 0,0, b2 + l*512, x, 2048, 1);
  }
  ln_kernel<<<4096, 128, 0, stream>>>(x, lnf_s, lnf_b, h);
  // logits = h @ W_lm + b_lm  (M=4096,N=32000,K=512)
  gemm_k<128,128,64,2,2,true,false,false,false><<<dim3(250,32,1), b256, 0, stream>>>(
      h, 512, 0,0,  wlmT, 512, 0,0,
      logits, 32000, 0,0, b_lm, nullptr, 512, 1);
  zero_kernel<<<1, 1, 0, stream>>>(lacc);
  loss_kernel<<<4096, b256, 0, stream>>>(logits, targets, lacc);
  final_kernel<<<1, 1, 0, stream>>>(lacc, logits + 131072000LL);
}